// Round 13
// baseline (182.448 us; speedup 1.0000x reference)
//
#include <hip/hip_runtime.h>
#include <hip/hip_bf16.h>

#define DIMK 512
#define NROWS 131072

typedef __bf16 bf16x8 __attribute__((ext_vector_type(8)));
typedef float f32x4 __attribute__((ext_vector_type(4)));

// fragment-ordered bf16 W: [nblk(32)][kchunk(64)][l15(16)][8k]
__device__ __attribute__((aligned(16))) unsigned short g_Wt2[DIMK * DIMK];
// ROW-MAJOR bf16 compacted masked rows: g_A[pos][k]
__device__ __attribute__((aligned(16))) unsigned short g_A[(size_t)NROWS * DIMK];
__device__ int g_rows[NROWS];   // compact pos -> original row
__device__ int g_cnt[1];

static __device__ __forceinline__ void gload_lds16(const unsigned short* g, unsigned short* l) {
    __builtin_amdgcn_global_load_lds(
        (const __attribute__((address_space(1))) void*)(unsigned long)(g),
        (__attribute__((address_space(3))) void*)(unsigned long)(l), 16, 0, 0);
}

static __device__ __forceinline__ unsigned short f2bf(float f) {
    unsigned u = __builtin_bit_cast(unsigned, f);
    u += 0x7FFFu + ((u >> 16) & 1u);
    return (unsigned short)(u >> 16);
}

// ---------- W[k][n] fp32 -> fragment-ordered bf16 (also resets g_cnt) ----------
__global__ void wprep_kernel(const float* __restrict__ W) {
    if (blockIdx.x == 0 && threadIdx.x == 0) g_cnt[0] = 0;
    __shared__ float tile[64][65];
    const int bk = blockIdx.x & 7;
    const int bn = blockIdx.x >> 3;
    const int t = threadIdx.x;       // 256
    const int rl = t >> 2;
    const int ch = t & 3;

    const float* src = W + (bk * 64 + rl) * DIMK + bn * 64 + ch * 16;
    float4 v[4];
#pragma unroll
    for (int i = 0; i < 4; i++) v[i] = reinterpret_cast<const float4*>(src)[i];
#pragma unroll
    for (int i = 0; i < 4; i++) {
        tile[rl][ch * 16 + i * 4 + 0] = v[i].x;
        tile[rl][ch * 16 + i * 4 + 1] = v[i].y;
        tile[rl][ch * 16 + i * 4 + 2] = v[i].z;
        tile[rl][ch * 16 + i * 4 + 3] = v[i].w;
    }
    __syncthreads();

    unsigned short o[16];
#pragma unroll
    for (int i = 0; i < 16; i++) o[i] = f2bf(tile[ch * 16 + i][rl]);
    const int nblk = bn * 4 + (rl >> 4);
    const int kchunk = bk * 8 + ch * 2;
    unsigned short* dst = g_Wt2 + nblk * 8192 + kchunk * 128 + (rl & 15) * 8;
    *reinterpret_cast<uint4*>(dst) = *reinterpret_cast<uint4*>(&o[0]);
    *reinterpret_cast<uint4*>(dst + 128) = *reinterpret_cast<uint4*>(&o[8]);
}

// ---------- fused: dtype-detect + ballot partition + copy/convert ----------
// block owns 64 rows; wave 0 ballots (1 atomic), positions via LDS;
// batch-8 MLP loads (PLAIN, so L3 residue of X hits); NT stores on out only.
__global__ __launch_bounds__(256)
void prep_kernel(const float* __restrict__ X, const void* __restrict__ maskp,
                 float* __restrict__ out) {
    __shared__ int s_flags;  // bit0: word>1 => byte mask; bit1: odd word nonzero => int32
    __shared__ int s_pos[64];
    const int b = blockIdx.x;     // 2048
    const int t = threadIdx.x;    // 256
    if (t == 0) s_flags = 0;
    __syncthreads();
    {   // detection window: words [0,32768) of mask buffer — in-bounds for all dtypes
        unsigned w = ((const unsigned*)maskp)[(b & 127) * 256 + t];
        int fl = (w > 1u) ? 1 : 0;
        if ((t & 1) && w != 0u) fl |= 2;
        if (fl) atomicOr(&s_flags, fl);
    }
    __syncthreads();
    const int fl = s_flags;
    const int md = (fl & 1) ? 0 : ((fl & 2) ? 1 : 2);

    if (t < 64) {  // wave 0: partition this block's 64 rows
        const int row = b * 64 + t;
        bool pred;
        if (md == 0)      pred = ((const unsigned char*)maskp)[row] != 0;
        else if (md == 1) pred = ((const int*)maskp)[row] != 0;
        else              pred = ((const unsigned*)maskp)[2l * row] != 0;
        unsigned long long bal = __ballot(pred);
        int pre = __popcll(bal & ((1ull << t) - 1ull));
        int cnt = __popcll(bal);
        int base = 0;
        if (t == 0 && cnt) base = atomicAdd(&g_cnt[0], cnt);
        base = __shfl(base, 0);
        const int pos = base + pre;
        if (pred) g_rows[pos] = row;
        s_pos[t] = pred ? pos : -1;
    }
    __syncthreads();

    const int wid = t >> 6;
    const int lane = t & 63;
    const long r0 = (long)b * 64 + wid * 16;

    int pos16[16];
#pragma unroll
    for (int i = 0; i < 16; i++) pos16[i] = s_pos[wid * 16 + i];

#pragma unroll
    for (int ii = 0; ii < 16; ii += 8) {
        f32x4 v[8][2];
#pragma unroll
        for (int j = 0; j < 8; j++) {
            const f32x4* src = reinterpret_cast<const f32x4*>(X + (r0 + ii + j) * DIMK);
            v[j][0] = src[2 * lane];       // plain load: let L3 residue hit
            v[j][1] = src[2 * lane + 1];
        }
#pragma unroll
        for (int j = 0; j < 8; j++) {
            const int p = pos16[ii + j];   // wave-uniform
            if (p >= 0) {
                unsigned short o[8];
                o[0] = f2bf(v[j][0][0]); o[1] = f2bf(v[j][0][1]);
                o[2] = f2bf(v[j][0][2]); o[3] = f2bf(v[j][0][3]);
                o[4] = f2bf(v[j][1][0]); o[5] = f2bf(v[j][1][1]);
                o[6] = f2bf(v[j][1][2]); o[7] = f2bf(v[j][1][3]);
                *reinterpret_cast<uint4*>(g_A + (long)p * DIMK + lane * 8) =
                    *reinterpret_cast<uint4*>(&o[0]);
            } else {
                f32x4* d = reinterpret_cast<f32x4*>(out + (r0 + ii + j) * DIMK);
                __builtin_nontemporal_store(v[j][0], &d[2 * lane]);
                __builtin_nontemporal_store(v[j][1], &d[2 * lane + 1]);
            }
        }
    }
}

// ---------- GEMM, m97 recipe: gload_lds A (row-major gather -> linear LDS) + B ----------
// ---------- (fragment order), single buffer, full-drain barriers ----------
__global__ __launch_bounds__(256, 3)
void gemm_kernel(float* __restrict__ out) {
    __shared__ __attribute__((aligned(16))) unsigned short Als[8192];  // 16KB: [g(8)][c(8)][j(16)][8]
    __shared__ __attribute__((aligned(16))) unsigned short Bls[8192];  // 16KB: [n(8)][c(8)][16][8]

    const int nmask = g_cnt[0];
    // XCD-balanced swizzle: tm strides across XCDs; 4 tn-siblings stay on one XCD.
    const int x = blockIdx.x & 7;
    const int q = blockIdx.x >> 3;           // 0..511
    const int tm = (q >> 2) * 8 + x;         // 0..1023
    const int tn = q & 3;
    if (tm * 128 >= nmask) return;

    const int t = threadIdx.x;
    const int lane = t & 63;
    const int wid = t >> 6, wr = wid >> 1, wc = wid & 1;
    const int l15 = lane & 15, lhi = lane >> 4;

    // A staging: wave wid stages 16-row groups {2*wid, 2*wid+1}; per group per kt,
    // 2 instrs; instr i: lane covers (row j = lane&15, chunk c = i*4 + lane>>4)
    // source = row-major g_A; LDS linear => layout [c(8)][j(16)][8k] per kt-slab
    const unsigned short* asrc[2][2];
#pragma unroll
    for (int g = 0; g < 2; g++)
#pragma unroll
        for (int i = 0; i < 2; i++)
            asrc[g][i] = g_A + ((long)(tm * 8 + wid * 2 + g) * 16 + (lane & 15)) * DIMK
                             + (i * 4 + (lane >> 4)) * 8;
    const unsigned short* bsrc = g_Wt2 + ((long)tn * 8 + wid * 2) * 8192 + lane * 8;
    unsigned short* adst = Als + (wid * 2) * 1024;   // wave-uniform; HW adds lane*16B
    unsigned short* bdst = Bls + (wid * 2) * 1024;

    f32x4 acc[4][4] = {};

    const unsigned aro = (wr * 4) * 1024 + lhi * 128 + l15 * 8;  // + m*1024 + s*512
    const unsigned bro = (wc * 4) * 1024 + lhi * 128 + l15 * 8;  // + n*1024 + s*512

#pragma unroll 1
    for (int kt = 0; kt < 8; kt++) {
#pragma unroll
        for (int g = 0; g < 2; g++) {
#pragma unroll
            for (int i = 0; i < 2; i++) {
                gload_lds16(asrc[g][i] + kt * 64, adst + g * 1024 + i * 512);
                gload_lds16(bsrc + g * 8192 + kt * 1024 + i * 512,
                            bdst + g * 1024 + i * 512);
            }
        }
        __syncthreads();   // drains vmcnt(0): tiles resident

#pragma unroll
        for (int s = 0; s < 2; s++) {
            bf16x8 afr[4], bfr[4];
#pragma unroll
            for (int m = 0; m < 4; m++)
                afr[m] = *reinterpret_cast<const bf16x8*>(Als + aro + m * 1024 + s * 512);
#pragma unroll
            for (int n = 0; n < 4; n++)
                bfr[n] = *reinterpret_cast<const bf16x8*>(Bls + bro + n * 1024 + s * 512);
#pragma unroll
            for (int m = 0; m < 4; m++)
#pragma unroll
                for (int n = 0; n < 4; n++)
                    acc[m][n] = __builtin_amdgcn_mfma_f32_16x16x32_bf16(
                        afr[m], bfr[n], acc[m][n], 0, 0, 0);
        }
        __syncthreads();   // reads done before next overwrite
    }

    // epilogue: C/D col = l15, row = lhi*4 + j; scatter back via g_rows
    const int colb = tn * 128 + wc * 64;
#pragma unroll
    for (int m = 0; m < 4; m++) {
        const int rl_ = wr * 64 + m * 16 + lhi * 4;
#pragma unroll
        for (int j = 0; j < 4; j++) {
            const int pos = tm * 128 + rl_ + j;
            if (pos < nmask) {
                const long rg = g_rows[pos];
                float* orow = out + rg * DIMK + colb;
#pragma unroll
                for (int n = 0; n < 4; n++)
                    orow[n * 16 + l15] = acc[m][n][j];
            }
        }
    }
}

extern "C" void kernel_launch(void* const* d_in, const int* in_sizes, int n_in,
                              void* d_out, int out_size, void* d_ws, size_t ws_size,
                              hipStream_t stream) {
    const float* X = (const float*)d_in[0];
    const void* mask = d_in[1];
    const float* W = (const float*)d_in[2];
    float* out = (float*)d_out;

    hipLaunchKernelGGL(wprep_kernel, dim3(64), dim3(256), 0, stream, W);
    hipLaunchKernelGGL(prep_kernel, dim3(NROWS / 64), dim3(256), 0, stream, X, mask, out);
    hipLaunchKernelGGL(gemm_kernel, dim3(4096), dim3(256), 0, stream, out);
}

// Round 14
// 157.388 us; speedup vs baseline: 1.1592x; 1.1592x over previous
//
#include <hip/hip_runtime.h>
#include <hip/hip_bf16.h>

#define DIMK 512
#define NROWS 131072

typedef __bf16 bf16x8 __attribute__((ext_vector_type(8)));
typedef float f32x4 __attribute__((ext_vector_type(4)));

// fragment-ordered bf16 W: [nblk(32)][kchunk(64)][l15(16)][8k]
__device__ __attribute__((aligned(16))) unsigned short g_Wt2[DIMK * DIMK];
// ROW-MAJOR bf16 compacted masked rows: g_A[pos][k]
__device__ __attribute__((aligned(16))) unsigned short g_A[(size_t)NROWS * DIMK];
__device__ int g_rows[NROWS];   // compact pos -> original row
__device__ int g_cnt[1];

static __device__ __forceinline__ void gload_lds16(const unsigned short* g, unsigned short* l) {
    __builtin_amdgcn_global_load_lds(
        (const __attribute__((address_space(1))) void*)(unsigned long)(g),
        (__attribute__((address_space(3))) void*)(unsigned long)(l), 16, 0, 0);
}

static __device__ __forceinline__ unsigned short f2bf(float f) {
    unsigned u = __builtin_bit_cast(unsigned, f);
    u += 0x7FFFu + ((u >> 16) & 1u);
    return (unsigned short)(u >> 16);
}

// ---------- W[k][n] fp32 -> fragment-ordered bf16 (also resets g_cnt) ----------
__global__ void wprep_kernel(const float* __restrict__ W) {
    if (blockIdx.x == 0 && threadIdx.x == 0) g_cnt[0] = 0;
    __shared__ float tile[64][65];
    const int bk = blockIdx.x & 7;
    const int bn = blockIdx.x >> 3;
    const int t = threadIdx.x;       // 256
    const int rl = t >> 2;
    const int ch = t & 3;

    const float* src = W + (bk * 64 + rl) * DIMK + bn * 64 + ch * 16;
    float4 v[4];
#pragma unroll
    for (int i = 0; i < 4; i++) v[i] = reinterpret_cast<const float4*>(src)[i];
#pragma unroll
    for (int i = 0; i < 4; i++) {
        tile[rl][ch * 16 + i * 4 + 0] = v[i].x;
        tile[rl][ch * 16 + i * 4 + 1] = v[i].y;
        tile[rl][ch * 16 + i * 4 + 2] = v[i].z;
        tile[rl][ch * 16 + i * 4 + 3] = v[i].w;
    }
    __syncthreads();

    unsigned short o[16];
#pragma unroll
    for (int i = 0; i < 16; i++) o[i] = f2bf(tile[ch * 16 + i][rl]);
    const int nblk = bn * 4 + (rl >> 4);
    const int kchunk = bk * 8 + ch * 2;
    unsigned short* dst = g_Wt2 + nblk * 8192 + kchunk * 128 + (rl & 15) * 8;
    *reinterpret_cast<uint4*>(dst) = *reinterpret_cast<uint4*>(&o[0]);
    *reinterpret_cast<uint4*>(dst + 128) = *reinterpret_cast<uint4*>(&o[8]);
}

// ---------- fused: dtype-detect + ballot partition + copy/convert ----------
// r12 version (measured 165.5 total): NT loads on X, NT stores on out.
__global__ __launch_bounds__(256)
void prep_kernel(const float* __restrict__ X, const void* __restrict__ maskp,
                 float* __restrict__ out) {
    __shared__ int s_flags;  // bit0: word>1 => byte mask; bit1: odd word nonzero => int32
    __shared__ int s_pos[64];
    const int b = blockIdx.x;     // 2048
    const int t = threadIdx.x;    // 256
    if (t == 0) s_flags = 0;
    __syncthreads();
    {   // detection window: words [0,32768) of mask buffer — in-bounds for all dtypes
        unsigned w = ((const unsigned*)maskp)[(b & 127) * 256 + t];
        int fl = (w > 1u) ? 1 : 0;
        if ((t & 1) && w != 0u) fl |= 2;
        if (fl) atomicOr(&s_flags, fl);
    }
    __syncthreads();
    const int fl = s_flags;
    const int md = (fl & 1) ? 0 : ((fl & 2) ? 1 : 2);

    if (t < 64) {  // wave 0: partition this block's 64 rows
        const int row = b * 64 + t;
        bool pred;
        if (md == 0)      pred = ((const unsigned char*)maskp)[row] != 0;
        else if (md == 1) pred = ((const int*)maskp)[row] != 0;
        else              pred = ((const unsigned*)maskp)[2l * row] != 0;
        unsigned long long bal = __ballot(pred);
        int pre = __popcll(bal & ((1ull << t) - 1ull));
        int cnt = __popcll(bal);
        int base = 0;
        if (t == 0 && cnt) base = atomicAdd(&g_cnt[0], cnt);
        base = __shfl(base, 0);
        const int pos = base + pre;
        if (pred) g_rows[pos] = row;
        s_pos[t] = pred ? pos : -1;
    }
    __syncthreads();

    const int wid = t >> 6;
    const int lane = t & 63;
    const long r0 = (long)b * 64 + wid * 16;

    int pos16[16];
#pragma unroll
    for (int i = 0; i < 16; i++) pos16[i] = s_pos[wid * 16 + i];

#pragma unroll
    for (int ii = 0; ii < 16; ii += 8) {
        f32x4 v[8][2];
#pragma unroll
        for (int j = 0; j < 8; j++) {
            const f32x4* src = reinterpret_cast<const f32x4*>(X + (r0 + ii + j) * DIMK);
            v[j][0] = __builtin_nontemporal_load(&src[2 * lane]);
            v[j][1] = __builtin_nontemporal_load(&src[2 * lane + 1]);
        }
#pragma unroll
        for (int j = 0; j < 8; j++) {
            const int p = pos16[ii + j];   // wave-uniform
            if (p >= 0) {
                unsigned short o[8];
                o[0] = f2bf(v[j][0][0]); o[1] = f2bf(v[j][0][1]);
                o[2] = f2bf(v[j][0][2]); o[3] = f2bf(v[j][0][3]);
                o[4] = f2bf(v[j][1][0]); o[5] = f2bf(v[j][1][1]);
                o[6] = f2bf(v[j][1][2]); o[7] = f2bf(v[j][1][3]);
                *reinterpret_cast<uint4*>(g_A + (long)p * DIMK + lane * 8) =
                    *reinterpret_cast<uint4*>(&o[0]);
            } else {
                f32x4* d = reinterpret_cast<f32x4*>(out + (r0 + ii + j) * DIMK);
                __builtin_nontemporal_store(v[j][0], &d[2 * lane]);
                __builtin_nontemporal_store(v[j][1], &d[2 * lane + 1]);
            }
        }
    }
}

// ---------- GEMM, m97 recipe, 128x256 tile: 512 threads = 8 waves (2M x 4N), ----------
// ---------- per-wave 64x64 (identical fragment code), LDS 48KB, 3 blocks/CU ----------
__global__ __launch_bounds__(512)
void gemm_kernel(float* __restrict__ out) {
    __shared__ __attribute__((aligned(16))) unsigned short Als[8192];   // 16KB: [g(8)][c(8)][j(16)][8]
    __shared__ __attribute__((aligned(16))) unsigned short Bls[16384];  // 32KB: [n(16)][c(8)][16][8]

    const int nmask = g_cnt[0];
    // XCD swizzle: tm strides across XCDs; tn-siblings (bid, bid+8) same XCD.
    const int x = blockIdx.x & 7;
    const int q = blockIdx.x >> 3;           // 0..255
    const int tm = (q >> 1) * 8 + x;         // 0..1023
    const int tn = q & 1;
    if (tm * 128 >= nmask) return;

    const int t = threadIdx.x;
    const int lane = t & 63;
    const int wid = t >> 6;                  // 0..7
    const int wr = wid >> 2, wc = wid & 3;   // 2M x 4N
    const int l15 = lane & 15, lhi = lane >> 4;

    // A staging: wave wid stages 16-row group wid; instr i: lane covers
    // (row j = lane&15, chunk c = i*4 + lane>>4) from row-major g_A.
    const unsigned short* asrc[2];
#pragma unroll
    for (int i = 0; i < 2; i++)
        asrc[i] = g_A + ((long)(tm * 8 + wid) * 16 + (lane & 15)) * DIMK
                      + (i * 4 + (lane >> 4)) * 8;
    // B staging: wave wid stages nblks {2*wid, 2*wid+1} (fragment-ordered linear)
    const unsigned short* bsrc = g_Wt2 + ((long)tn * 16 + wid * 2) * 8192 + lane * 8;
    unsigned short* adst = Als + wid * 1024;        // wave-uniform; HW adds lane*16B
    unsigned short* bdst = Bls + (wid * 2) * 1024;

    f32x4 acc[4][4] = {};

    const unsigned aro = (wr * 4) * 1024 + lhi * 128 + l15 * 8;  // + m*1024 + s*512
    const unsigned bro = (wc * 4) * 1024 + lhi * 128 + l15 * 8;  // + n*1024 + s*512

#pragma unroll 1
    for (int kt = 0; kt < 8; kt++) {
#pragma unroll
        for (int i = 0; i < 2; i++) {
            gload_lds16(asrc[i] + kt * 64, adst + i * 512);
#pragma unroll
            for (int g = 0; g < 2; g++)
                gload_lds16(bsrc + g * 8192 + kt * 1024 + i * 512,
                            bdst + g * 1024 + i * 512);
        }
        __syncthreads();   // drains vmcnt(0): tiles resident

#pragma unroll
        for (int s = 0; s < 2; s++) {
            bf16x8 afr[4], bfr[4];
#pragma unroll
            for (int m = 0; m < 4; m++)
                afr[m] = *reinterpret_cast<const bf16x8*>(Als + aro + m * 1024 + s * 512);
#pragma unroll
            for (int n = 0; n < 4; n++)
                bfr[n] = *reinterpret_cast<const bf16x8*>(Bls + bro + n * 1024 + s * 512);
#pragma unroll
            for (int m = 0; m < 4; m++)
#pragma unroll
                for (int n = 0; n < 4; n++)
                    acc[m][n] = __builtin_amdgcn_mfma_f32_16x16x32_bf16(
                        afr[m], bfr[n], acc[m][n], 0, 0, 0);
        }
        __syncthreads();   // reads done before next overwrite
    }

    // epilogue: C/D col = l15, row = lhi*4 + j; scatter back via g_rows
    const int colb = tn * 256 + wc * 64;
#pragma unroll
    for (int m = 0; m < 4; m++) {
        const int rl_ = wr * 64 + m * 16 + lhi * 4;
#pragma unroll
        for (int j = 0; j < 4; j++) {
            const int pos = tm * 128 + rl_ + j;
            if (pos < nmask) {
                const long rg = g_rows[pos];
                float* orow = out + rg * DIMK + colb;
#pragma unroll
                for (int n = 0; n < 4; n++)
                    orow[n * 16 + l15] = acc[m][n][j];
            }
        }
    }
}

extern "C" void kernel_launch(void* const* d_in, const int* in_sizes, int n_in,
                              void* d_out, int out_size, void* d_ws, size_t ws_size,
                              hipStream_t stream) {
    const float* X = (const float*)d_in[0];
    const void* mask = d_in[1];
    const float* W = (const float*)d_in[2];
    float* out = (float*)d_out;

    hipLaunchKernelGGL(wprep_kernel, dim3(64), dim3(256), 0, stream, W);
    hipLaunchKernelGGL(prep_kernel, dim3(NROWS / 64), dim3(256), 0, stream, X, mask, out);
    hipLaunchKernelGGL(gemm_kernel, dim3(2048), dim3(512), 0, stream, out);
}